// Round 3
// baseline (102.672 us; speedup 1.0000x reference)
//
#include <hip/hip_runtime.h>
#include <hip/hip_bf16.h>

// Problem constants (fixed by the reference file):
//   B=16 docs, PREV(K)=768, D(N)=256, lengths[i]=1024+128*i, T=31744, MAXLEN=2944
// Doc start offsets are multiples of 128 -> 64-row M-tiles never straddle docs.

#define T_TOTAL 31744
#define K_DIM   768
#define N_DIM   256
#define MAXLEN  2944

typedef __attribute__((ext_vector_type(8))) short    bf16x8;
typedef __attribute__((ext_vector_type(4))) short    short4v;
typedef __attribute__((ext_vector_type(4))) float    f32x4;
typedef __attribute__((ext_vector_type(4))) unsigned u32x4;

__device__ __forceinline__ unsigned short f2bf(float f) {
  unsigned u = __builtin_bit_cast(unsigned, f);
  u += 0x7fffu + ((u >> 16) & 1u);
  return (unsigned short)(u >> 16);
}

// v_cvt_pk_bf16_f32: one instr converts 2 f32 -> packed 2 bf16 (RNE).
__device__ __forceinline__ unsigned cvtpk(float lo, float hi) {
  unsigned r;
  asm("v_cvt_pk_bf16_f32 %0, %1, %2" : "=v"(r) : "v"(lo), "v"(hi));
  return r;
}

// ---------------------------------------------------------------------------
// Kernel 1: W [768][256] f32  ->  Wt [256][768] bf16 (workspace)
// ---------------------------------------------------------------------------
__global__ __launch_bounds__(256) void wt_transpose(const float* __restrict__ W,
                                                    unsigned short* __restrict__ Wt) {
  __shared__ unsigned short tile[64][68];
  const int b  = blockIdx.x;
  const int k0 = (b % 12) * 64;
  const int n0 = (b / 12) * 64;
  const int tid = threadIdx.x;
  const int rr = tid >> 4;
  const int cc = tid & 15;

#pragma unroll
  for (int i = 0; i < 4; ++i) {
    const int kr = i * 16 + rr;
    f32x4 v = *(const f32x4*)(W + (size_t)(k0 + kr) * N_DIM + n0 + cc * 4);
    tile[kr][cc * 4 + 0] = f2bf(v[0]);
    tile[kr][cc * 4 + 1] = f2bf(v[1]);
    tile[kr][cc * 4 + 2] = f2bf(v[2]);
    tile[kr][cc * 4 + 3] = f2bf(v[3]);
  }
  __syncthreads();
#pragma unroll
  for (int i = 0; i < 4; ++i) {
    const int nr = i * 16 + rr;
    short4v o;
#pragma unroll
    for (int j = 0; j < 4; ++j) o[j] = (short)tile[cc * 4 + j][nr];
    *(short4v*)(Wt + (size_t)(n0 + nr) * K_DIM + k0 + cc * 4) = o;
  }
}

// ---------------------------------------------------------------------------
// Kernel 2: zero only the padding rows of the [16*2944, 256] f32 output.
// ---------------------------------------------------------------------------
__global__ __launch_bounds__(256) void zero_pad(float* __restrict__ out) {
  const int gid = blockIdx.x * 256 + threadIdx.x;
  const int row = gid >> 6;
  const int doc = row / MAXLEN;
  const int within = row - doc * MAXLEN;
  const int len = 1024 + 128 * doc;
  if (within >= len) {
    f32x4 z = {0.f, 0.f, 0.f, 0.f};
    *(f32x4*)(out + (size_t)gid * 4) = z;
  }
}

// ---------------------------------------------------------------------------
// Kernel 3: GEMM + scatter — no LDS, no barriers, rolled ping-pong pipeline.
// 512 threads = 8 waves (2M x 4N); BM=64, BN=256; per-wave tile 32x64 via
// 2x4 frags of mfma_f32_16x16x32_bf16 (acc = 32 VGPR). A-frags loaded direct
// from global fp32 in MFMA lane layout + v_cvt_pk_bf16_f32; B-frags direct
// from bf16 Wt (L2-resident). Named ping-pong buffers across a ROLLED loop
// backedge so the compiler cannot collapse the prefetch (round-2 lesson:
// full unroll let it resequence loads against uses -> VGPR 84, no pipeline).
// ---------------------------------------------------------------------------
__global__ __launch_bounds__(512, 4) void gemm_scatter(const float* __restrict__ A,
                                                       const unsigned short* __restrict__ Wt,
                                                       const float* __restrict__ bias,
                                                       float* __restrict__ out) {
  const int tid  = threadIdx.x;
  const int wid  = tid >> 6;
  const int lane = tid & 63;
  const int l15  = lane & 15;
  const int l4   = lane >> 4;
  const int wr   = wid >> 2;     // 0..1  (M half)
  const int wc   = wid & 3;      // 0..3  (N quarter)
  const int t0   = blockIdx.x * 64;

  // which doc does this tile live in (tiles never straddle docs)
  int off = 0, doc = 0;
  while (doc < 15) {
    const int len = 1024 + 128 * doc;
    if (t0 < off + len) break;
    off += len; ++doc;
  }
  const long tgt0 = (long)doc * MAXLEN + (t0 - off);

  const float*          aBase = A  + (size_t)(t0 + wr * 32 + l15) * K_DIM + l4 * 8;
  const unsigned short* bBase = Wt + (size_t)(wc * 64 + l15) * K_DIM + l4 * 8;

  f32x4 acc[2][4];
#pragma unroll
  for (int m = 0; m < 2; ++m)
#pragma unroll
    for (int n = 0; n < 4; ++n) acc[m][n] = f32x4{0.f, 0.f, 0.f, 0.f};

  // ping-pong register buffers (named, static indexing only)
  f32x4  a0[2][2], a1[2][2];   // [m-frag][16B half]
  bf16x8 b0[4],    b1[4];      // [n-frag]

#define LOADA(dst, kb)                                                              \
  {                                                                                 \
    _Pragma("unroll") for (int m = 0; m < 2; ++m) {                                 \
      dst[m][0] = *(const f32x4*)(aBase + (size_t)m * 16 * K_DIM + (kb));           \
      dst[m][1] = *(const f32x4*)(aBase + (size_t)m * 16 * K_DIM + (kb) + 4);       \
    }                                                                               \
  }
#define LOADB(dst, kb)                                                              \
  {                                                                                 \
    _Pragma("unroll") for (int n = 0; n < 4; ++n) {                                 \
      dst[n] = *(const bf16x8*)(bBase + (size_t)n * 16 * K_DIM + (kb));             \
    }                                                                               \
  }
#define CVT(af, src)                                                                \
  {                                                                                 \
    _Pragma("unroll") for (int m = 0; m < 2; ++m) {                                 \
      u32x4 u;                                                                      \
      u[0] = cvtpk(src[m][0][0], src[m][0][1]);                                     \
      u[1] = cvtpk(src[m][0][2], src[m][0][3]);                                     \
      u[2] = cvtpk(src[m][1][0], src[m][1][1]);                                     \
      u[3] = cvtpk(src[m][1][2], src[m][1][3]);                                     \
      af[m] = __builtin_bit_cast(bf16x8, u);                                        \
    }                                                                               \
  }
#define MFMA(af, bsrc)                                                              \
  {                                                                                 \
    _Pragma("unroll") for (int m = 0; m < 2; ++m)                                   \
      _Pragma("unroll") for (int n = 0; n < 4; ++n)                                 \
        acc[m][n] = __builtin_amdgcn_mfma_f32_16x16x32_bf16(af[m], bsrc[n],         \
                                                            acc[m][n], 0, 0, 0);    \
  }

  // prologue: steps s=0 (buf0), s=1 (buf1)
  LOADA(a0, 0)
  LOADB(b0, 0)
  LOADA(a1, 32)
  LOADB(b1, 32)

  // main: 11 pairs with reloads; loads issued in iter p are consumed in p+1.
#pragma unroll 1
  for (int p = 0; p < 11; ++p) {
    const int kb = p * 64;
    bf16x8 af[2];

    CVT(af, a0)              // waits on a0 (issued last iteration)
    LOADA(a0, kb + 64)       // prefetch step s=2p+2
    MFMA(af, b0)
    LOADB(b0, kb + 64)

    CVT(af, a1)
    LOADA(a1, kb + 96)       // prefetch step s=2p+3
    MFMA(af, b1)
    LOADB(b1, kb + 96)
  }

  // tail pair: s=22, s=23 (no reloads)
  {
    bf16x8 af[2];
    CVT(af, a0)
    MFMA(af, b0)
    CVT(af, a1)
    MFMA(af, b1)
  }

  // epilogue: bias + scatter to padded rows
  float bc[4];
#pragma unroll
  for (int n = 0; n < 4; ++n) bc[n] = bias[wc * 64 + n * 16 + l15];

#pragma unroll
  for (int m = 0; m < 2; ++m)
#pragma unroll
    for (int n = 0; n < 4; ++n) {
      const size_t base = (size_t)(tgt0 + wr * 32 + m * 16 + l4 * 4) * N_DIM
                        + wc * 64 + n * 16 + l15;
#pragma unroll
      for (int j = 0; j < 4; ++j)
        out[base + (size_t)j * N_DIM] = acc[m][n][j] + bc[n];
    }
#undef LOADA
#undef LOADB
#undef CVT
#undef MFMA
}

// ---------------------------------------------------------------------------
extern "C" void kernel_launch(void* const* d_in, const int* in_sizes, int n_in,
                              void* d_out, int out_size, void* d_ws, size_t ws_size,
                              hipStream_t stream) {
  const float* A    = (const float*)d_in[0];   // [31744, 768]
  const float* W    = (const float*)d_in[1];   // [768, 256]
  const float* bias = (const float*)d_in[2];   // [256]
  float* out = (float*)d_out;                  // [16, 2944, 256]
  unsigned short* Wt = (unsigned short*)d_ws;  // [256][768] bf16

  wt_transpose<<<48, 256, 0, stream>>>(W, Wt);
  zero_pad<<<(16 * MAXLEN * 64) / 256, 256, 0, stream>>>(out);
  gemm_scatter<<<T_TOTAL / 64, 512, 0, stream>>>(A, Wt, bias, out);
}

// Round 5
// 79.404 us; speedup vs baseline: 1.2930x; 1.2930x over previous
//
#include <hip/hip_runtime.h>
#include <hip/hip_bf16.h>

// Problem constants (fixed by the reference file):
//   B=16 docs, PREV(K)=768, D(N)=256, lengths[i]=1024+128*i, T=31744, MAXLEN=2944
// Doc start offsets are multiples of 128 -> 64-row M-tiles never straddle docs.

#define T_TOTAL 31744
#define K_DIM   768
#define N_DIM   256
#define MAXLEN  2944
#define NKT     24          // K_DIM / 32

typedef __attribute__((ext_vector_type(8))) short    bf16x8;
typedef __attribute__((ext_vector_type(4))) short    short4v;
typedef __attribute__((ext_vector_type(4))) float    f32x4;
typedef __attribute__((ext_vector_type(4))) unsigned u32x4;

__device__ __forceinline__ unsigned short f2bf(float f) {
  unsigned u = __builtin_bit_cast(unsigned, f);
  u += 0x7fffu + ((u >> 16) & 1u);
  return (unsigned short)(u >> 16);
}

__device__ __forceinline__ unsigned cvtpk(float lo, float hi) {
  unsigned r;
  asm("v_cvt_pk_bf16_f32 %0, %1, %2" : "=v"(r) : "v"(lo), "v"(hi));
  return r;
}

// async global->LDS, 16B per lane; LDS dest = wave-uniform base + lane*16
__device__ __forceinline__ void gload16(const void* g, void* l) {
  __builtin_amdgcn_global_load_lds(
      (const __attribute__((address_space(1))) unsigned int*)g,
      (__attribute__((address_space(3))) unsigned int*)l,
      16, 0, 0);
}

// ---------------------------------------------------------------------------
// Kernel 1: W [768][256] f32  ->  Wt [256][768] bf16 (workspace)
// ---------------------------------------------------------------------------
__global__ __launch_bounds__(256) void wt_transpose(const float* __restrict__ W,
                                                    unsigned short* __restrict__ Wt) {
  __shared__ unsigned short tile[64][68];
  const int b  = blockIdx.x;
  const int k0 = (b % 12) * 64;
  const int n0 = (b / 12) * 64;
  const int tid = threadIdx.x;
  const int rr = tid >> 4;
  const int cc = tid & 15;

#pragma unroll
  for (int i = 0; i < 4; ++i) {
    const int kr = i * 16 + rr;
    f32x4 v = *(const f32x4*)(W + (size_t)(k0 + kr) * N_DIM + n0 + cc * 4);
    tile[kr][cc * 4 + 0] = f2bf(v[0]);
    tile[kr][cc * 4 + 1] = f2bf(v[1]);
    tile[kr][cc * 4 + 2] = f2bf(v[2]);
    tile[kr][cc * 4 + 3] = f2bf(v[3]);
  }
  __syncthreads();
#pragma unroll
  for (int i = 0; i < 4; ++i) {
    const int nr = i * 16 + rr;
    short4v o;
#pragma unroll
    for (int j = 0; j < 4; ++j) o[j] = (short)tile[cc * 4 + j][nr];
    *(short4v*)(Wt + (size_t)(n0 + nr) * K_DIM + k0 + cc * 4) = o;
  }
}

// ---------------------------------------------------------------------------
// Kernel 2: zero only the padding rows of the [16*2944, 256] f32 output.
// ---------------------------------------------------------------------------
__global__ __launch_bounds__(256) void zero_pad(float* __restrict__ out) {
  const int gid = blockIdx.x * 256 + threadIdx.x;
  const int row = gid >> 6;
  const int doc = row / MAXLEN;
  const int within = row - doc * MAXLEN;
  const int len = 1024 + 128 * doc;
  if (within >= len) {
    f32x4 z = {0.f, 0.f, 0.f, 0.f};
    *(f32x4*)(out + (size_t)gid * 4) = z;
  }
}

// ---------------------------------------------------------------------------
// Kernel 3: GEMM + scatter — m97-style 2-phase global_load_lds pipeline.
// BM=64, BN=256(full D), BK=32; 512 threads = 8 waves (2M x 4N), per-wave
// 32x64 tile (2x4 frags of mfma_f32_16x16x32_bf16).
//
// LDS layouts are k-group-major so fragment ds_read_b128 is conflict-free:
//   A buf (8KB f32):   slot16 = g*64 + row   -> g = tid>>6 (=wid), row = tid&63
//   B buf (16KB bf16): slot16 = h*256 + col  -> h = tid>>8 (+2 for chunk1), col = tid&255
// (global_load_lds dest is linear: slot16 == tid, so the SOURCE address per
//  lane must follow the slot decomposition above — round-4 bug was using
//  tid>>3/tid&7 for A, which staged a row-major image under a g-major reader.)
// ---------------------------------------------------------------------------
__global__ __launch_bounds__(512, 6) void gemm_scatter(const float* __restrict__ A,
                                                       const unsigned short* __restrict__ Wt,
                                                       const float* __restrict__ bias,
                                                       float* __restrict__ out) {
  __shared__ f32x4 AbV[2][512];    // 2 x 8KB
  __shared__ f32x4 BbV[2][1024];   // 2 x 16KB

  const int tid  = threadIdx.x;
  const int wid  = tid >> 6;
  const int lane = tid & 63;
  const int l15  = lane & 15;
  const int l4   = lane >> 4;
  const int wr   = wid >> 2;     // 0..1  (M half)
  const int wc   = wid & 3;      // 0..3  (N quarter)
  const int t0   = blockIdx.x * 64;

  // which doc does this tile live in (tiles never straddle docs)
  int off = 0, doc = 0;
  while (doc < 15) {
    const int len = 1024 + 128 * doc;
    if (t0 < off + len) break;
    off += len; ++doc;
  }
  const long tgt0 = (long)doc * MAXLEN + (t0 - off);

  // ---- staging source addresses (per lane) ----
  // A: slot16 = tid = g*64 + row  ->  g = tid>>6 (wave-uniform), row = tid&63
  const int rowA = tid & 63;
  const int gA   = tid >> 6;
  const float* pA = A + (size_t)(t0 + rowA) * K_DIM + gA * 4;
  // B: chunk0 slot16 = tid = h*256 + col -> h = tid>>8, col = tid&255; chunk1 h += 2
  const int colB = tid & 255;
  const int hB   = tid >> 8;
  const unsigned short* pB0 = Wt + (size_t)colB * K_DIM + hB * 8;
  const unsigned short* pB1 = pB0 + 16;

  // ---- wave-uniform LDS staging bases ----
  char* ldsA = (char*)&AbV[0][0];
  char* ldsB = (char*)&BbV[0][0];
  char* ldsAw = ldsA + wid * 1024;
  char* ldsBw = ldsB + wid * 1024;

  // ---- fragment read offsets ----
  const int aoff = (l4 * 2) * 1024 + (wr * 32 + l15) * 16;
  const int boff = l4 * 4096 + (wc * 64 + l15) * 16;

  f32x4 acc[2][4];
#pragma unroll
  for (int m = 0; m < 2; ++m)
#pragma unroll
    for (int n = 0; n < 4; ++n) acc[m][n] = f32x4{0.f, 0.f, 0.f, 0.f};

#define STAGE(buf, kb)                                                   \
  {                                                                      \
    gload16(pA + (kb), ldsAw + (buf) * 8192);                            \
    gload16(pB0 + (kb), ldsBw + (buf) * 16384);                          \
    gload16(pB1 + (kb), ldsBw + (buf) * 16384 + 8192);                   \
  }

#define COMPUTE(buf)                                                     \
  {                                                                      \
    const char* ab = ldsA + (buf) * 8192 + aoff;                         \
    const char* bb = ldsB + (buf) * 16384 + boff;                        \
    bf16x8 bf0 = *(const bf16x8*)(bb);                                   \
    bf16x8 bf1 = *(const bf16x8*)(bb + 256);                             \
    bf16x8 bf2 = *(const bf16x8*)(bb + 512);                             \
    bf16x8 bf3 = *(const bf16x8*)(bb + 768);                             \
    _Pragma("unroll") for (int m = 0; m < 2; ++m) {                      \
      f32x4 av0 = *(const f32x4*)(ab + m * 256);                         \
      f32x4 av1 = *(const f32x4*)(ab + m * 256 + 1024);                  \
      u32x4 u;                                                           \
      u[0] = cvtpk(av0[0], av0[1]); u[1] = cvtpk(av0[2], av0[3]);        \
      u[2] = cvtpk(av1[0], av1[1]); u[3] = cvtpk(av1[2], av1[3]);        \
      bf16x8 af = __builtin_bit_cast(bf16x8, u);                         \
      acc[m][0] = __builtin_amdgcn_mfma_f32_16x16x32_bf16(af, bf0, acc[m][0], 0, 0, 0); \
      acc[m][1] = __builtin_amdgcn_mfma_f32_16x16x32_bf16(af, bf1, acc[m][1], 0, 0, 0); \
      acc[m][2] = __builtin_amdgcn_mfma_f32_16x16x32_bf16(af, bf2, acc[m][2], 0, 0, 0); \
      acc[m][3] = __builtin_amdgcn_mfma_f32_16x16x32_bf16(af, bf3, acc[m][3], 0, 0, 0); \
    }                                                                    \
  }

  // prologue: stage tile 0, drain, barrier
  STAGE(0, 0)
  __syncthreads();

  // main loop: issue stage(t+1), compute(t), barrier (drains vmcnt+lgkmcnt)
#pragma unroll 1
  for (int t = 0; t < NKT - 1; ++t) {
    STAGE((t + 1) & 1, (t + 1) * 32)
    COMPUTE(t & 1)
    __syncthreads();
  }
  COMPUTE((NKT - 1) & 1)

  // epilogue: bias + scatter to padded rows
  float bc[4];
#pragma unroll
  for (int n = 0; n < 4; ++n) bc[n] = bias[wc * 64 + n * 16 + l15];

#pragma unroll
  for (int m = 0; m < 2; ++m)
#pragma unroll
    for (int n = 0; n < 4; ++n) {
      const size_t base = (size_t)(tgt0 + wr * 32 + m * 16 + l4 * 4) * N_DIM
                        + wc * 64 + n * 16 + l15;
#pragma unroll
      for (int j = 0; j < 4; ++j)
        out[base + (size_t)j * N_DIM] = acc[m][n][j] + bc[n];
    }
#undef STAGE
#undef COMPUTE
}

// ---------------------------------------------------------------------------
extern "C" void kernel_launch(void* const* d_in, const int* in_sizes, int n_in,
                              void* d_out, int out_size, void* d_ws, size_t ws_size,
                              hipStream_t stream) {
  const float* A    = (const float*)d_in[0];   // [31744, 768]
  const float* W    = (const float*)d_in[1];   // [768, 256]
  const float* bias = (const float*)d_in[2];   // [256]
  float* out = (float*)d_out;                  // [16, 2944, 256]
  unsigned short* Wt = (unsigned short*)d_ws;  // [256][768] bf16

  wt_transpose<<<48, 256, 0, stream>>>(W, Wt);
  zero_pad<<<(16 * MAXLEN * 64) / 256, 256, 0, stream>>>(out);
  gemm_scatter<<<T_TOTAL / 64, 512, 0, stream>>>(A, Wt, bias, out);
}

// Round 6
// 38.964 us; speedup vs baseline: 2.6350x; 2.0379x over previous
//
#include <hip/hip_runtime.h>
#include <hip/hip_bf16.h>

// Problem constants (fixed by the reference file):
//   B=16 docs, PREV(K)=768, D(N)=256, lengths[i]=1024+128*i, T=31744, MAXLEN=2944
// Doc start offsets are multiples of 128 -> 64-row M-tiles never straddle docs.

#define T_TOTAL 31744
#define K_DIM   768
#define N_DIM   256
#define MAXLEN  2944
#define NKT     24          // K_DIM / 32

typedef __attribute__((ext_vector_type(8))) short    bf16x8;
typedef __attribute__((ext_vector_type(4))) float    f32x4;
typedef __attribute__((ext_vector_type(4))) unsigned u32x4;

__device__ __forceinline__ unsigned short f2bf(float f) {
  unsigned u = __builtin_bit_cast(unsigned, f);
  u += 0x7fffu + ((u >> 16) & 1u);
  return (unsigned short)(u >> 16);
}

__device__ __forceinline__ unsigned cvtpk(float lo, float hi) {
  unsigned r;
  asm("v_cvt_pk_bf16_f32 %0, %1, %2" : "=v"(r) : "v"(lo), "v"(hi));
  return r;
}

// async global->LDS, 16B per lane; LDS dest = wave-uniform base + lane*16
__device__ __forceinline__ void gload16(const void* g, void* l) {
  __builtin_amdgcn_global_load_lds(
      (const __attribute__((address_space(1))) unsigned int*)g,
      (__attribute__((address_space(3))) unsigned int*)l,
      16, 0, 0);
}

// ---------------------------------------------------------------------------
// Kernel 1: W [768][256] f32 -> Wt_tiled bf16, laid out in EXACT per-K-step
// LDS image order: element (kt, h, col, e) = bf16(W[kt*32 + h*8 + e][col]),
// flat index ((kt*4 + h)*256 + col)*8.  One block per kt (24 blocks).
// GEMM staging of B is then a contiguous 16KB copy per K-step.
// ---------------------------------------------------------------------------
__global__ __launch_bounds__(256) void wt_tile(const float* __restrict__ W,
                                               unsigned short* __restrict__ Wt) {
  __shared__ float Wl[32][257];     // +1 pad
  const int kt  = blockIdx.x;       // 0..23
  const int tid = threadIdx.x;

#pragma unroll
  for (int i = 0; i < 8; ++i) {
    const int idx = i * 256 + tid;          // 0..2047 chunks of f32x4
    const int row = idx >> 6;
    const int c4  = idx & 63;
    f32x4 v = *(const f32x4*)(W + (size_t)(kt * 32 + row) * N_DIM + c4 * 4);
    Wl[row][c4 * 4 + 0] = v[0];
    Wl[row][c4 * 4 + 1] = v[1];
    Wl[row][c4 * 4 + 2] = v[2];
    Wl[row][c4 * 4 + 3] = v[3];
  }
  __syncthreads();

#pragma unroll
  for (int h = 0; h < 4; ++h) {
    bf16x8 ov;
#pragma unroll
    for (int e = 0; e < 8; ++e) ov[e] = (short)f2bf(Wl[h * 8 + e][tid]);
    *(bf16x8*)(Wt + (((size_t)kt * 4 + h) * 256 + tid) * 8) = ov;
  }
}

// ---------------------------------------------------------------------------
// Kernel 2: zero only the padding rows of the [16*2944, 256] f32 output.
// ---------------------------------------------------------------------------
__global__ __launch_bounds__(256) void zero_pad(float* __restrict__ out) {
  const int gid = blockIdx.x * 256 + threadIdx.x;
  const int row = gid >> 6;
  const int doc = row / MAXLEN;
  const int within = row - doc * MAXLEN;
  const int len = 1024 + 128 * doc;
  if (within >= len) {
    f32x4 z = {0.f, 0.f, 0.f, 0.f};
    *(f32x4*)(out + (size_t)gid * 4) = z;
  }
}

// ---------------------------------------------------------------------------
// Kernel 3: GEMM + scatter — 2-phase global_load_lds pipeline, COALESCED
// staging (round-5 lesson: k-group-major sources had 64 lines/instr; now
// ~8-16 contiguous segments/instr).
//   A image (8KB/buf):  slot16 = row*8 + g'  with g' = g ^ (row&7)  (XOR swz)
//       stage source: lane tid -> row = tid>>3, g = (tid&7)^(row&7)
//       frag read:    arow*128 + ((2*l4+j)^(arow&7))*16  -> 32 banks / 16 lanes
//   B image (16KB/buf): slot16 = h*256 + col, pre-arranged in Wt_tiled so the
//       stage is a contiguous 16KB copy; frag read l4*4096 + col*16 (conflict-free).
// BM=64, BN=256, BK=32; 512 threads = 8 waves (2M x 4N), per-wave 32x64.
// ---------------------------------------------------------------------------
__global__ __launch_bounds__(512, 6) void gemm_scatter(const float* __restrict__ A,
                                                       const unsigned short* __restrict__ Wt,
                                                       const float* __restrict__ bias,
                                                       float* __restrict__ out) {
  __shared__ f32x4 AbV[2][512];    // 2 x 8KB
  __shared__ f32x4 BbV[2][1024];   // 2 x 16KB

  const int tid  = threadIdx.x;
  const int wid  = tid >> 6;
  const int lane = tid & 63;
  const int l15  = lane & 15;
  const int l4   = lane >> 4;
  const int wr   = wid >> 2;     // 0..1  (M half)
  const int wc   = wid & 3;      // 0..3  (N quarter)
  const int t0   = blockIdx.x * 64;

  // which doc does this tile live in (tiles never straddle docs)
  int off = 0, doc = 0;
  while (doc < 15) {
    const int len = 1024 + 128 * doc;
    if (t0 < off + len) break;
    off += len; ++doc;
  }
  const long tgt0 = (long)doc * MAXLEN + (t0 - off);

  // ---- staging source addresses (per lane) ----
  // A: slot16 = tid = row*8 + g'; source group g = g' ^ (row&7)
  const int rowA = tid >> 3;
  const int gA   = (tid & 7) ^ (rowA & 7);
  const float* pA = A + (size_t)(t0 + rowA) * K_DIM + gA * 4;
  // B: contiguous from Wt_tiled; per step offset kt*8192 elements (16KB)
  const unsigned short* pB = Wt + (size_t)tid * 8;

  // ---- wave-uniform LDS staging bases ----
  char* ldsA  = (char*)&AbV[0][0];
  char* ldsB  = (char*)&BbV[0][0];
  char* ldsAw = ldsA + wid * 1024;
  char* ldsBw = ldsB + wid * 1024;

  // ---- fragment read offsets ----
  const int s_a   = l15 & 7;
  const int arow0 = wr * 32 + l15;
  const int aoff0 = arow0 * 128 + (((l4 << 1)    ) ^ s_a) * 16;  // k = l4*8 .. +3
  const int aoff1 = arow0 * 128 + (((l4 << 1) | 1) ^ s_a) * 16;  // k = l4*8+4 .. +7
  const int boff  = l4 * 4096 + (wc * 64 + l15) * 16;

  f32x4 acc[2][4];
#pragma unroll
  for (int m = 0; m < 2; ++m)
#pragma unroll
    for (int n = 0; n < 4; ++n) acc[m][n] = f32x4{0.f, 0.f, 0.f, 0.f};

#define STAGE(buf, kt_)                                                  \
  {                                                                      \
    gload16(pA + (kt_) * 32, ldsAw + (buf) * 8192);                      \
    gload16(pB + (size_t)(kt_) * 8192, ldsBw + (buf) * 16384);           \
    gload16(pB + (size_t)(kt_) * 8192 + 4096,                            \
            ldsBw + (buf) * 16384 + 8192);                               \
  }

#define COMPUTE(buf)                                                     \
  {                                                                      \
    const char* ab = ldsA + (buf) * 8192;                                \
    const char* bb = ldsB + (buf) * 16384 + boff;                        \
    bf16x8 bf0 = *(const bf16x8*)(bb);                                   \
    bf16x8 bf1 = *(const bf16x8*)(bb + 256);                             \
    bf16x8 bf2 = *(const bf16x8*)(bb + 512);                             \
    bf16x8 bf3 = *(const bf16x8*)(bb + 768);                             \
    _Pragma("unroll") for (int m = 0; m < 2; ++m) {                      \
      f32x4 av0 = *(const f32x4*)(ab + aoff0 + m * 2048);                \
      f32x4 av1 = *(const f32x4*)(ab + aoff1 + m * 2048);                \
      u32x4 u;                                                           \
      u[0] = cvtpk(av0[0], av0[1]); u[1] = cvtpk(av0[2], av0[3]);        \
      u[2] = cvtpk(av1[0], av1[1]); u[3] = cvtpk(av1[2], av1[3]);        \
      bf16x8 af = __builtin_bit_cast(bf16x8, u);                         \
      acc[m][0] = __builtin_amdgcn_mfma_f32_16x16x32_bf16(af, bf0, acc[m][0], 0, 0, 0); \
      acc[m][1] = __builtin_amdgcn_mfma_f32_16x16x32_bf16(af, bf1, acc[m][1], 0, 0, 0); \
      acc[m][2] = __builtin_amdgcn_mfma_f32_16x16x32_bf16(af, bf2, acc[m][2], 0, 0, 0); \
      acc[m][3] = __builtin_amdgcn_mfma_f32_16x16x32_bf16(af, bf3, acc[m][3], 0, 0, 0); \
    }                                                                    \
  }

  // prologue: stage tile 0, barrier (implies vmcnt drain)
  STAGE(0, 0)
  __syncthreads();

  // main loop: issue stage(t+1), compute(t), barrier
#pragma unroll 1
  for (int t = 0; t < NKT - 1; ++t) {
    STAGE((t + 1) & 1, t + 1)
    COMPUTE(t & 1)
    __syncthreads();
  }
  COMPUTE((NKT - 1) & 1)

  // epilogue: bias + scatter to padded rows
  float bc[4];
#pragma unroll
  for (int n = 0; n < 4; ++n) bc[n] = bias[wc * 64 + n * 16 + l15];

#pragma unroll
  for (int m = 0; m < 2; ++m)
#pragma unroll
    for (int n = 0; n < 4; ++n) {
      const size_t base = (size_t)(tgt0 + wr * 32 + m * 16 + l4 * 4) * N_DIM
                        + wc * 64 + n * 16 + l15;
#pragma unroll
      for (int j = 0; j < 4; ++j)
        out[base + (size_t)j * N_DIM] = acc[m][n][j] + bc[n];
    }
#undef STAGE
#undef COMPUTE
}

// ---------------------------------------------------------------------------
extern "C" void kernel_launch(void* const* d_in, const int* in_sizes, int n_in,
                              void* d_out, int out_size, void* d_ws, size_t ws_size,
                              hipStream_t stream) {
  const float* A    = (const float*)d_in[0];   // [31744, 768]
  const float* W    = (const float*)d_in[1];   // [768, 256]
  const float* bias = (const float*)d_in[2];   // [256]
  float* out = (float*)d_out;                  // [16, 2944, 256]
  unsigned short* Wt = (unsigned short*)d_ws;  // Wt_tiled bf16 [24][4][256][8]

  wt_tile<<<24, 256, 0, stream>>>(W, Wt);
  zero_pad<<<(16 * MAXLEN * 64) / 256, 256, 0, stream>>>(out);
  gemm_scatter<<<T_TOTAL / 64, 512, 0, stream>>>(A, Wt, bias, out);
}